// Round 1
// baseline (192.862 us; speedup 1.0000x reference)
//
#include <hip/hip_runtime.h>
#include <math.h>

#define NBUCKET 4096
#define NCOPY   8
#define CAP     8192
#define TOPK    100
#define NLVL    3
#define NCLS    80

// ---------------------------------------------------------------------------
// Shared prob computation: 16 threads per anchor, thread handles classes
// sub, sub+16, sub+32, sub+48, sub+64.  Used by BOTH hist and compact so the
// fp results are bit-identical between passes.
// ---------------------------------------------------------------------------
__device__ __forceinline__ void compute_probs(const float* __restrict__ conf,
                                              const float* __restrict__ cls,
                                              int a, int sub, float p[5])
{
    float cv  = conf[a];
    float sig = 1.0f / (1.0f + expf(-cv));
    const float* row = cls + (size_t)a * NCLS + sub;
    float c0 = row[0], c1 = row[16], c2 = row[32], c3 = row[48], c4 = row[64];
    float m = fmaxf(fmaxf(fmaxf(c0, c1), fmaxf(c2, c3)), c4);
#pragma unroll
    for (int o = 8; o >= 1; o >>= 1) m = fmaxf(m, __shfl_xor(m, o, 16));
    float e0 = expf(c0 - m), e1 = expf(c1 - m), e2 = expf(c2 - m),
          e3 = expf(c3 - m), e4 = expf(c4 - m);
    float s = ((e0 + e1) + (e2 + e3)) + e4;
#pragma unroll
    for (int o = 8; o >= 1; o >>= 1) s += __shfl_xor(s, o, 16);
    float inv = sig / s;
    p[0] = e0 * inv; p[1] = e1 * inv; p[2] = e2 * inv; p[3] = e3 * inv; p[4] = e4 * inv;
}

// ---------------------------------------------------------------------------
// Pass A: histogram of float-bit keys (>>18 -> 4096 buckets, monotonic for
// non-negative floats).  Shared hist per block, merged into NCOPY global
// copies to spread atomic contention.
// ---------------------------------------------------------------------------
__global__ void hist_kernel(const float* __restrict__ conf,
                            const float* __restrict__ cls,
                            int nAnchors,
                            unsigned int* __restrict__ ghist)
{
    __shared__ unsigned int sh[NBUCKET];
    for (int b = threadIdx.x; b < NBUCKET; b += blockDim.x) sh[b] = 0;
    __syncthreads();

    int sub    = threadIdx.x & 15;
    int lane16 = threadIdx.x >> 4;
    int nChunk = nAnchors >> 4;           // anchors are multiples of 16
    for (int ch = blockIdx.x; ch < nChunk; ch += gridDim.x) {
        int a = (ch << 4) + lane16;
        float p[5];
        compute_probs(conf, cls, a, sub, p);
#pragma unroll
        for (int k = 0; k < 5; k++) {
            unsigned b = __float_as_uint(p[k]) >> 18;
            if (b > NBUCKET - 1) b = NBUCKET - 1;
            atomicAdd(&sh[b], 1u);
        }
    }
    __syncthreads();
    unsigned int* g = ghist + (blockIdx.x & (NCOPY - 1)) * NBUCKET;
    for (int b = threadIdx.x; b < NBUCKET; b += blockDim.x) {
        unsigned v = sh[b];
        if (v) atomicAdd(&g[b], v);
    }
}

// ---------------------------------------------------------------------------
// Scan: per level (blockIdx.x), find bucket B such that the count of elements
// in buckets >= B first reaches >= TOPK.  Threshold key = B << 18.
// ---------------------------------------------------------------------------
__global__ void scan_kernel(const unsigned int* __restrict__ ghist,
                            unsigned int* __restrict__ thresh)
{
    int lvl = blockIdx.x;
    const unsigned int* h0 = ghist + lvl * NCOPY * NBUCKET;
    __shared__ unsigned int h[NBUCKET];
    __shared__ unsigned int ps[256];
    int t = threadIdx.x;
    for (int b = t; b < NBUCKET; b += 256) {
        unsigned s = 0;
        for (int c = 0; c < NCOPY; c++) s += h0[c * NBUCKET + b];
        h[b] = s;
    }
    __syncthreads();
    // chunk t covers the t-th 16-bucket chunk counting DOWN from bucket 4095
    unsigned cs = 0;
#pragma unroll
    for (int i = 0; i < 16; i++) cs += h[NBUCKET - 1 - (t * 16 + i)];
    ps[t] = cs;
    __syncthreads();
    for (int o = 1; o < 256; o <<= 1) {
        unsigned v = (t >= o) ? ps[t - o] : 0u;
        __syncthreads();
        ps[t] += v;
        __syncthreads();
    }
    unsigned incl = ps[t], excl = incl - cs;
    if (excl < TOPK && incl >= TOPK) {
        unsigned cum = excl, B = 0;
        for (int i = 0; i < 16; i++) {
            int b = NBUCKET - 1 - (t * 16 + i);
            cum += h[b];
            if (cum >= TOPK) { B = (unsigned)b; break; }
        }
        thresh[lvl] = B << 18;
    }
}

// ---------------------------------------------------------------------------
// Pass B: recompute probs (cls now L3-resident) and compact everything whose
// key >= threshold into (score, flat_idx) candidate lists.
// ---------------------------------------------------------------------------
__global__ void compact_kernel(const float* __restrict__ conf,
                               const float* __restrict__ cls,
                               int nAnchors,
                               const unsigned int* __restrict__ thresh, int lvl,
                               unsigned int* __restrict__ ccount,
                               float* __restrict__ cscore,
                               unsigned int* __restrict__ cidx)
{
    unsigned T = thresh[lvl];
    int sub    = threadIdx.x & 15;
    int lane16 = threadIdx.x >> 4;
    int nChunk = nAnchors >> 4;
    float*        cs = cscore + lvl * CAP;
    unsigned int* ci = cidx   + lvl * CAP;
    for (int ch = blockIdx.x; ch < nChunk; ch += gridDim.x) {
        int a = (ch << 4) + lane16;
        float p[5];
        compute_probs(conf, cls, a, sub, p);
#pragma unroll
        for (int k = 0; k < 5; k++) {
            unsigned key = __float_as_uint(p[k]);
            if (key >= T) {
                unsigned pos = atomicAdd(&ccount[lvl], 1u);
                if (pos < CAP) {
                    cs[pos] = p[k];
                    ci[pos] = (unsigned)(a * NCLS + sub + 16 * k);
                }
            }
        }
    }
}

// ---------------------------------------------------------------------------
// Finalize: exact per-level top-100 (rank selection, tie-break = idx asc to
// match lax.top_k), box decode, global stable sort (score desc, pos asc to
// match stable argsort(-scores)), bitmask greedy NMS identical to the
// reference fori_loop recurrence, output write.
// ---------------------------------------------------------------------------
__global__ __launch_bounds__(1024) void finalize_kernel(
    const float* __restrict__ reg1, const float* __restrict__ anch1,
    const float* __restrict__ reg2, const float* __restrict__ anch2,
    const float* __restrict__ reg3, const float* __restrict__ anch3,
    const float* __restrict__ cscore, const unsigned int* __restrict__ cidx,
    const unsigned int* __restrict__ ccount,
    float* __restrict__ out)
{
    int tid = threadIdx.x;
    __shared__ float s_score[300];
    __shared__ int   s_idx[300];
    __shared__ float s_box[300][4];
    __shared__ int   s_label[300];
    __shared__ int   s_valid[300];
    __shared__ float t_score[300];
    __shared__ float t_box[300][4];
    __shared__ int   t_label[300];
    __shared__ int   t_valid[300];
    __shared__ unsigned long long sup[300][5];
    __shared__ unsigned long long keepw[5];

    if (tid < 300) { s_score[tid] = -1e30f; s_idx[tid] = 0; }
    __syncthreads();

    // per-level top-100 by rank selection
    for (int lvl = 0; lvl < NLVL; lvl++) {
        int cnt = min((int)ccount[lvl], CAP);
        const float*        sc = cscore + lvl * CAP;
        const unsigned int* ix = cidx   + lvl * CAP;
        for (int c = tid; c < cnt; c += 1024) {
            float    my  = sc[c];
            unsigned myi = ix[c];
            int rank = 0;
            for (int k = 0; k < cnt; k++) {
                float v = sc[k];
                rank += (v > my) || (v == my && ix[k] < myi);
            }
            if (rank < TOPK) {
                s_score[lvl * TOPK + rank] = my;
                s_idx[lvl * TOPK + rank]   = (int)myi;
            }
        }
    }
    __syncthreads();

    // box decode for the 300 candidates (level-concatenated order)
    if (tid < 300) {
        int lvl = tid / TOPK;
        const float* reg = lvl == 0 ? reg1 : (lvl == 1 ? reg2 : reg3);
        const float* anc = lvl == 0 ? anch1 : (lvl == 1 ? anch2 : anch3);
        float stride = lvl == 0 ? 8.0f : (lvl == 1 ? 16.0f : 32.0f);
        int idx = s_idx[tid];
        int a   = idx / NCLS;
        int lab = idx % NCLS;
        float r0 = reg[4 * a + 0], r1 = reg[4 * a + 1], r2 = reg[4 * a + 2], r3 = reg[4 * a + 3];
        float a0 = anc[4 * a + 0], a1 = anc[4 * a + 1], a2 = anc[4 * a + 2], a3 = anc[4 * a + 3];
        float cx = (1.0f / (1.0f + expf(-r0)) + a0) * stride;
        float cy = (1.0f / (1.0f + expf(-r1)) + a1) * stride;
        float w  = expf(r2) * a2;
        float h  = expf(r3) * a3;
        s_box[tid][0] = cx - 0.5f * w;
        s_box[tid][1] = cy - 0.5f * h;
        s_box[tid][2] = cx + 0.5f * w;
        s_box[tid][3] = cy + 0.5f * h;
        s_label[tid] = lab;
        s_valid[tid] = s_score[tid] > 0.001f;   // CONF_TH
    }
    __syncthreads();

    // global stable sort: key (score desc, position asc)
    if (tid < 300) {
        float my = s_score[tid];
        int rank = 0;
        for (int k = 0; k < 300; k++) {
            float v = s_score[k];
            rank += (v > my) || (v == my && k < tid);
        }
        t_score[rank]  = my;
        t_label[rank]  = s_label[tid];
        t_valid[rank]  = s_valid[tid];
        t_box[rank][0] = s_box[tid][0];
        t_box[rank][1] = s_box[tid][1];
        t_box[rank][2] = s_box[tid][2];
        t_box[rank][3] = s_box[tid][3];
    }
    __syncthreads();

    // suppression matrix: sup[i][w] bit (j - 64w) set iff j>i, same label, IoU>0.5
    for (int p = tid; p < 300 * 5; p += 1024) {
        int i = p / 5, w = p % 5;
        unsigned long long bits = 0;
        float x1 = t_box[i][0], y1 = t_box[i][1], x2 = t_box[i][2], y2 = t_box[i][3];
        float areai = (x2 - x1) * (y2 - y1);
        int labi = t_label[i];
        int j0 = w * 64;
        int j1 = min(j0 + 64, 300);
        for (int j = max(j0, i + 1); j < j1; j++) {
            if (t_label[j] != labi) continue;
            float xx1 = fmaxf(x1, t_box[j][0]);
            float yy1 = fmaxf(y1, t_box[j][1]);
            float xx2 = fminf(x2, t_box[j][2]);
            float yy2 = fminf(y2, t_box[j][3]);
            float ww = fmaxf(1e-10f, xx2 - xx1);
            float hh = fmaxf(1e-10f, yy2 - yy1);
            float inter = ww * hh;
            float areaj = (t_box[j][2] - t_box[j][0]) * (t_box[j][3] - t_box[j][1]);
            float iou = inter / (areai + areaj - inter);
            if (iou > 0.5f) bits |= 1ull << (j - j0);
        }
        sup[i][w] = bits;
    }
    if (tid < 5) {
        unsigned long long kw = 0;
        for (int b = 0; b < 64; b++) {
            int j = tid * 64 + b;
            if (j < 300 && t_valid[j]) kw |= 1ull << b;
        }
        keepw[tid] = kw;
    }
    __syncthreads();

    // exact greedy recurrence: keep = keep & ~(sup[i] & keep[i])
    if (tid == 0) {
        unsigned long long k0 = keepw[0], k1 = keepw[1], k2 = keepw[2],
                           k3 = keepw[3], k4 = keepw[4];
        for (int i = 0; i < 300; i++) {
            int w = i >> 6, b = i & 63;
            unsigned long long cur = (w == 0) ? k0 : (w == 1) ? k1 : (w == 2) ? k2 : (w == 3) ? k3 : k4;
            if ((cur >> b) & 1ull) {
                k0 &= ~sup[i][0]; k1 &= ~sup[i][1]; k2 &= ~sup[i][2];
                k3 &= ~sup[i][3]; k4 &= ~sup[i][4];
            }
        }
        keepw[0] = k0; keepw[1] = k1; keepw[2] = k2; keepw[3] = k3; keepw[4] = k4;
    }
    __syncthreads();

    // output 300 x 6
    for (int e = tid; e < 300 * 6; e += 1024) {
        int row = e / 6, col = e % 6;
        bool kept = (keepw[row >> 6] >> (row & 63)) & 1ull;
        float v = 0.0f;
        if (kept) {
            if (col < 4) {
                v = t_box[row][col] * (1.0f / 2048.0f);
                v = fminf(fmaxf(v, 0.0f), 1.0f);
            } else if (col == 4) {
                v = t_score[row];
            } else {
                v = (float)t_label[row];
            }
        }
        out[e] = v;
    }
}

// ---------------------------------------------------------------------------
extern "C" void kernel_launch(void* const* d_in, const int* in_sizes, int n_in,
                              void* d_out, int out_size, void* d_ws, size_t ws_size,
                              hipStream_t stream)
{
    const float* conf1 = (const float*)d_in[0];
    const float* cls1  = (const float*)d_in[1];
    const float* reg1  = (const float*)d_in[2];
    const float* anch1 = (const float*)d_in[3];
    const float* conf2 = (const float*)d_in[4];
    const float* cls2  = (const float*)d_in[5];
    const float* reg2  = (const float*)d_in[6];
    const float* anch2 = (const float*)d_in[7];
    const float* conf3 = (const float*)d_in[8];
    const float* cls3  = (const float*)d_in[9];
    const float* reg3  = (const float*)d_in[10];
    const float* anch3 = (const float*)d_in[11];

    int N1 = in_sizes[0];   // 196608
    int N2 = in_sizes[4];   // 49152
    int N3 = in_sizes[8];   // 12288

    unsigned int* wsu    = (unsigned int*)d_ws;
    unsigned int* hist   = wsu;                               // [3][NCOPY][NBUCKET]
    unsigned int* thresh = wsu + NLVL * NCOPY * NBUCKET;      // [3]
    unsigned int* ccount = thresh + NLVL;                     // [3]
    float*        cscore = (float*)(wsu + NLVL * NCOPY * NBUCKET + 8);  // [3][CAP]
    unsigned int* cidx   = (unsigned int*)(cscore + NLVL * CAP);        // [3][CAP]

    hipMemsetAsync(d_ws, 0, (size_t)(NLVL * NCOPY * NBUCKET + 8) * sizeof(unsigned int), stream);

    hist_kernel<<<1024, 256, 0, stream>>>(conf1, cls1, N1, hist + 0 * NCOPY * NBUCKET);
    hist_kernel<<<384,  256, 0, stream>>>(conf2, cls2, N2, hist + 1 * NCOPY * NBUCKET);
    hist_kernel<<<128,  256, 0, stream>>>(conf3, cls3, N3, hist + 2 * NCOPY * NBUCKET);

    scan_kernel<<<NLVL, 256, 0, stream>>>(hist, thresh);

    compact_kernel<<<1024, 256, 0, stream>>>(conf1, cls1, N1, thresh, 0, ccount, cscore, cidx);
    compact_kernel<<<384,  256, 0, stream>>>(conf2, cls2, N2, thresh, 1, ccount, cscore, cidx);
    compact_kernel<<<128,  256, 0, stream>>>(conf3, cls3, N3, thresh, 2, ccount, cscore, cidx);

    finalize_kernel<<<1, 1024, 0, stream>>>(reg1, anch1, reg2, anch2, reg3, anch3,
                                            cscore, cidx, ccount, (float*)d_out);
}

// Round 2
// 149.158 us; speedup vs baseline: 1.2930x; 1.2930x over previous
//
#include <hip/hip_runtime.h>
#include <math.h>

#define NBUCKET 4096
#define NCOPY   8
#define CAP     8192
#define QCAP    4096
#define STAGE   4096
#define TOPK    100
#define NLVL    3
#define NCLS    80

// block counts per level for passA / compact
#define PA_G1 1024
#define PA_G2 256
#define PA_G3 64
#define CK_G1 192
#define CK_G2 48
#define CK_G3 12

// ---------------------------------------------------------------------------
// Pass A: per-anchor max prob (= sigmoid/sum, exact max of the 80 probs),
// stored to amax[]; histogram of its float-bit key (>>18, monotonic for
// positive floats).  ONE shared-mem atomic per anchor (not per score).
// 16 threads per anchor; thread `sub` covers classes sub, sub+16, ..., sub+64.
// ---------------------------------------------------------------------------
__global__ void passA_kernel(const float* __restrict__ conf1, const float* __restrict__ cls1,
                             const float* __restrict__ conf2, const float* __restrict__ cls2,
                             const float* __restrict__ conf3, const float* __restrict__ cls3,
                             int n1, int n2, int n3,
                             unsigned int* __restrict__ ghist,
                             float* __restrict__ amax)
{
    const float* conf; const float* cls; int nA, nb, b;
    unsigned int* gh; float* am;
    if (blockIdx.x < PA_G1) {
        b = blockIdx.x; conf = conf1; cls = cls1; nA = n1; nb = PA_G1;
        gh = ghist; am = amax;
    } else if (blockIdx.x < PA_G1 + PA_G2) {
        b = blockIdx.x - PA_G1; conf = conf2; cls = cls2; nA = n2; nb = PA_G2;
        gh = ghist + NCOPY * NBUCKET; am = amax + n1;
    } else {
        b = blockIdx.x - PA_G1 - PA_G2; conf = conf3; cls = cls3; nA = n3; nb = PA_G3;
        gh = ghist + 2 * NCOPY * NBUCKET; am = amax + n1 + n2;
    }

    __shared__ unsigned int sh[NBUCKET];
    for (int i = threadIdx.x; i < NBUCKET; i += 256) sh[i] = 0;
    __syncthreads();

    int sub = threadIdx.x & 15;
    int g16 = threadIdx.x >> 4;
    int nChunk = nA >> 4;
    for (int ch = b; ch < nChunk; ch += nb) {
        int a = (ch << 4) + g16;
        float cv  = conf[a];
        float sig = 1.0f / (1.0f + expf(-cv));
        const float* row = cls + (size_t)a * NCLS + sub;
        float c0 = row[0], c1 = row[16], c2 = row[32], c3 = row[48], c4 = row[64];
        float m = fmaxf(fmaxf(fmaxf(c0, c1), fmaxf(c2, c3)), c4);
#pragma unroll
        for (int o = 8; o >= 1; o >>= 1) m = fmaxf(m, __shfl_xor(m, o, 16));
        float s = ((expf(c0 - m) + expf(c1 - m)) + (expf(c2 - m) + expf(c3 - m))) + expf(c4 - m);
#pragma unroll
        for (int o = 8; o >= 1; o >>= 1) s += __shfl_xor(s, o, 16);
        float inv = sig / s;                 // == max over the 80 probs, exactly
        if (sub == 0) {
            am[a] = inv;
            unsigned bk = __float_as_uint(inv) >> 18;
            if (bk > NBUCKET - 1) bk = NBUCKET - 1;
            atomicAdd(&sh[bk], 1u);
        }
    }
    __syncthreads();
    unsigned int* g = gh + (b & (NCOPY - 1)) * NBUCKET;
    for (int i = threadIdx.x; i < NBUCKET; i += 256) {
        unsigned v = sh[i];
        if (v) atomicAdd(&g[i], v);
    }
}

// ---------------------------------------------------------------------------
// Scan: per level, smallest bucket B with (# anchor-maxes in buckets >= B)
// >= TOPK.  Threshold key = B<<18.  Also zeroes ccount for compact.
// ---------------------------------------------------------------------------
__global__ void scan_kernel(const unsigned int* __restrict__ ghist,
                            unsigned int* __restrict__ thresh,
                            unsigned int* __restrict__ ccount)
{
    int lvl = blockIdx.x;
    const unsigned int* h0 = ghist + lvl * NCOPY * NBUCKET;
    __shared__ unsigned int h[NBUCKET];
    __shared__ unsigned int ps[256];
    int t = threadIdx.x;
    if (t == 0) ccount[lvl] = 0;
    for (int bb = t; bb < NBUCKET; bb += 256) {
        unsigned s = 0;
        for (int c = 0; c < NCOPY; c++) s += h0[c * NBUCKET + bb];
        h[bb] = s;
    }
    __syncthreads();
    unsigned cs = 0;
#pragma unroll
    for (int i = 0; i < 16; i++) cs += h[NBUCKET - 1 - (t * 16 + i)];
    ps[t] = cs;
    __syncthreads();
    for (int o = 1; o < 256; o <<= 1) {
        unsigned v = (t >= o) ? ps[t - o] : 0u;
        __syncthreads();
        ps[t] += v;
        __syncthreads();
    }
    unsigned incl = ps[t], excl = incl - cs;
    if (excl < TOPK && incl >= TOPK) {
        unsigned cum = excl, B = 0;
        for (int i = 0; i < 16; i++) {
            int bb = NBUCKET - 1 - (t * 16 + i);
            cum += h[bb];
            if (cum >= TOPK) { B = (unsigned)bb; break; }
        }
        thresh[lvl] = B << 18;
    }
}

// ---------------------------------------------------------------------------
// Compact: scan the amax array (float4), queue qualifying anchors in LDS,
// then recompute their 80 probs (bit-identical 16-lane routine) and emit
// (score, flat_idx) for every class with key >= T (max class unconditional,
// guaranteeing >= TOPK candidates per level).
// ---------------------------------------------------------------------------
__global__ void compact_kernel(const float* __restrict__ conf1, const float* __restrict__ cls1,
                               const float* __restrict__ conf2, const float* __restrict__ cls2,
                               const float* __restrict__ conf3, const float* __restrict__ cls3,
                               int n1, int n2, int n3,
                               const unsigned int* __restrict__ thresh,
                               const float* __restrict__ amax,
                               unsigned int* __restrict__ ccount,
                               float* __restrict__ cscore,
                               unsigned int* __restrict__ cidx)
{
    const float* conf; const float* cls; int bl, lvl; const float* am;
    if (blockIdx.x < CK_G1)              { lvl = 0; bl = blockIdx.x;               conf = conf1; cls = cls1; am = amax; }
    else if (blockIdx.x < CK_G1 + CK_G2) { lvl = 1; bl = blockIdx.x - CK_G1;       conf = conf2; cls = cls2; am = amax + n1; }
    else                                 { lvl = 2; bl = blockIdx.x - CK_G1 - CK_G2; conf = conf3; cls = cls3; am = amax + n1 + n2; }

    __shared__ int qn;
    __shared__ int queue[QCAP];
    if (threadIdx.x == 0) qn = 0;
    __syncthreads();

    unsigned T = thresh[lvl];
    int idx4 = bl * 256 + threadIdx.x;
    const float4* am4 = (const float4*)am;
    float4 v = am4[idx4];
    float vv[4] = {v.x, v.y, v.z, v.w};
#pragma unroll
    for (int j = 0; j < 4; j++) {
        if (__float_as_uint(vv[j]) >= T) {
            int p = atomicAdd(&qn, 1);
            if (p < QCAP) queue[p] = idx4 * 4 + j;
        }
    }
    __syncthreads();
    int qcnt = min(qn, QCAP);
    int grp = threadIdx.x >> 4;
    int sub = threadIdx.x & 15;
    float*        csl = cscore + lvl * CAP;
    unsigned int* cil = cidx   + lvl * CAP;
    for (int q = grp; q < qcnt; q += 16) {
        int a = queue[q];
        float cv  = conf[a];
        float sig = 1.0f / (1.0f + expf(-cv));
        const float* row = cls + (size_t)a * NCLS + sub;
        float c0 = row[0], c1 = row[16], c2 = row[32], c3 = row[48], c4 = row[64];
        float m = fmaxf(fmaxf(fmaxf(c0, c1), fmaxf(c2, c3)), c4);
#pragma unroll
        for (int o = 8; o >= 1; o >>= 1) m = fmaxf(m, __shfl_xor(m, o, 16));
        float e0 = expf(c0 - m), e1 = expf(c1 - m), e2 = expf(c2 - m),
              e3 = expf(c3 - m), e4 = expf(c4 - m);
        float s = ((e0 + e1) + (e2 + e3)) + e4;
#pragma unroll
        for (int o = 8; o >= 1; o >>= 1) s += __shfl_xor(s, o, 16);
        float inv = sig / s;
        float e[5] = {e0, e1, e2, e3, e4};
#pragma unroll
        for (int k = 0; k < 5; k++) {
            float p = e[k] * inv;
            if (e[k] == 1.0f || __float_as_uint(p) >= T) {
                unsigned pos = atomicAdd(&ccount[lvl], 1u);
                if (pos < CAP) {
                    csl[pos] = p;
                    cil[pos] = (unsigned)(a * NCLS + sub + 16 * k);
                }
            }
        }
    }
}

// ---------------------------------------------------------------------------
// Finalize: LDS-staged exact per-level top-100 (rank selection, tie = idx
// asc), box decode, stable global sort (score desc, pos asc), register-
// resident wave NMS (exact greedy recurrence), output write.
// ---------------------------------------------------------------------------
__global__ __launch_bounds__(1024) void finalize_kernel(
    const float* __restrict__ reg1, const float* __restrict__ anch1,
    const float* __restrict__ reg2, const float* __restrict__ anch2,
    const float* __restrict__ reg3, const float* __restrict__ anch3,
    const float* __restrict__ cscore, const unsigned int* __restrict__ cidx,
    const unsigned int* __restrict__ ccount,
    float* __restrict__ out)
{
    int tid = threadIdx.x;
    __shared__ float        q_sc[STAGE];
    __shared__ unsigned int q_ix[STAGE];
    __shared__ float s_score[300];
    __shared__ int   s_idx[300];
    __shared__ float s_box[300][4];
    __shared__ int   s_label[300];
    __shared__ int   s_valid[300];
    __shared__ float t_score[300];
    __shared__ float t_box[300][4];
    __shared__ int   t_label[300];
    __shared__ int   t_valid[300];
    __shared__ unsigned long long sup[300][5];
    __shared__ unsigned long long keepw[5];

    if (tid < 300) { s_score[tid] = -1e30f; s_idx[tid] = 0; }

    // per-level top-100 by rank selection, candidates staged in LDS
    for (int lvl = 0; lvl < NLVL; lvl++) {
        int cnt = min((int)ccount[lvl], CAP);
        const float*        sc = cscore + lvl * CAP;
        const unsigned int* ix = cidx   + lvl * CAP;
        int n = min(cnt, STAGE);
        __syncthreads();
        for (int c = tid; c < n; c += 1024) { q_sc[c] = sc[c]; q_ix[c] = ix[c]; }
        __syncthreads();
        for (int c = tid; c < cnt; c += 1024) {
            float my; unsigned myi;
            if (c < n) { my = q_sc[c]; myi = q_ix[c]; }
            else       { my = sc[c];   myi = ix[c];   }
            int rank = 0;
            for (int k = 0; k < cnt; k++) {
                float v; unsigned vi;
                if (k < n) { v = q_sc[k]; vi = q_ix[k]; }
                else       { v = sc[k];   vi = ix[k];   }
                rank += (v > my) || (v == my && vi < myi);
            }
            if (rank < TOPK) {
                s_score[lvl * TOPK + rank] = my;
                s_idx[lvl * TOPK + rank]   = (int)myi;
            }
        }
    }
    __syncthreads();

    // box decode
    if (tid < 300) {
        int lvl = tid / TOPK;
        const float* reg = lvl == 0 ? reg1 : (lvl == 1 ? reg2 : reg3);
        const float* anc = lvl == 0 ? anch1 : (lvl == 1 ? anch2 : anch3);
        float stride = lvl == 0 ? 8.0f : (lvl == 1 ? 16.0f : 32.0f);
        int idx = s_idx[tid];
        int a   = idx / NCLS;
        int lab = idx % NCLS;
        float r0 = reg[4 * a + 0], r1 = reg[4 * a + 1], r2 = reg[4 * a + 2], r3 = reg[4 * a + 3];
        float a0 = anc[4 * a + 0], a1 = anc[4 * a + 1], a2 = anc[4 * a + 2], a3 = anc[4 * a + 3];
        float cx = (1.0f / (1.0f + expf(-r0)) + a0) * stride;
        float cy = (1.0f / (1.0f + expf(-r1)) + a1) * stride;
        float w  = expf(r2) * a2;
        float h  = expf(r3) * a3;
        s_box[tid][0] = cx - 0.5f * w;
        s_box[tid][1] = cy - 0.5f * h;
        s_box[tid][2] = cx + 0.5f * w;
        s_box[tid][3] = cy + 0.5f * h;
        s_label[tid] = lab;
        s_valid[tid] = s_score[tid] > 0.001f;
    }
    __syncthreads();

    // stable global sort: (score desc, position asc)
    if (tid < 300) {
        float my = s_score[tid];
        int rank = 0;
        for (int k = 0; k < 300; k++) {
            float v = s_score[k];
            rank += (v > my) || (v == my && k < tid);
        }
        t_score[rank]  = my;
        t_label[rank]  = s_label[tid];
        t_valid[rank]  = s_valid[tid];
        t_box[rank][0] = s_box[tid][0];
        t_box[rank][1] = s_box[tid][1];
        t_box[rank][2] = s_box[tid][2];
        t_box[rank][3] = s_box[tid][3];
    }
    __syncthreads();

    // suppression matrix (parallel build)
    for (int p = tid; p < 300 * 5; p += 1024) {
        int i = p / 5, w = p % 5;
        unsigned long long bits = 0;
        float x1 = t_box[i][0], y1 = t_box[i][1], x2 = t_box[i][2], y2 = t_box[i][3];
        float areai = (x2 - x1) * (y2 - y1);
        int labi = t_label[i];
        int j0 = w * 64;
        int j1 = min(j0 + 64, 300);
        for (int j = max(j0, i + 1); j < j1; j++) {
            if (t_label[j] != labi) continue;
            float xx1 = fmaxf(x1, t_box[j][0]);
            float yy1 = fmaxf(y1, t_box[j][1]);
            float xx2 = fminf(x2, t_box[j][2]);
            float yy2 = fminf(y2, t_box[j][3]);
            float ww = fmaxf(1e-10f, xx2 - xx1);
            float hh = fmaxf(1e-10f, yy2 - yy1);
            float inter = ww * hh;
            float areaj = (t_box[j][2] - t_box[j][0]) * (t_box[j][3] - t_box[j][1]);
            float iou = inter / (areai + areaj - inter);
            if (iou > 0.5f) bits |= 1ull << (j - j0);
        }
        sup[i][w] = bits;
    }
    if (tid < 5) {
        unsigned long long kw = 0;
        for (int bb = 0; bb < 64; bb++) {
            int j = tid * 64 + bb;
            if (j < 300 && t_valid[j]) kw |= 1ull << bb;
        }
        keepw[tid] = kw;
    }
    __syncthreads();

    // register-resident wave NMS: lane l of wave 0 owns rows l, l+64, ...
    if (tid < 64) {
        int l = tid;
        unsigned long long s0[5], s1[5], s2[5], s3[5], s4[5];
#pragma unroll
        for (int w = 0; w < 5; w++) {
            s0[w] = sup[l][w];
            s1[w] = sup[l + 64][w];
            s2[w] = sup[l + 128][w];
            s3[w] = sup[l + 192][w];
            s4[w] = (l + 256 < 300) ? sup[l + 256][w] : 0ull;
        }
        unsigned long long k0 = keepw[0], k1 = keepw[1], k2 = keepw[2],
                           k3 = keepw[3], k4 = keepw[4];
#define NMS_STEP(SR, KR, B)                                                   \
        {                                                                     \
            unsigned long long msk = 0ull - (unsigned long long)((KR >> (B)) & 1ull); \
            k0 &= ~(__shfl(SR[0], (B)) & msk);                                \
            k1 &= ~(__shfl(SR[1], (B)) & msk);                                \
            k2 &= ~(__shfl(SR[2], (B)) & msk);                                \
            k3 &= ~(__shfl(SR[3], (B)) & msk);                                \
            k4 &= ~(__shfl(SR[4], (B)) & msk);                                \
        }
#pragma unroll 8
        for (int b = 0; b < 64; b++) NMS_STEP(s0, k0, b)
#pragma unroll 8
        for (int b = 0; b < 64; b++) NMS_STEP(s1, k1, b)
#pragma unroll 8
        for (int b = 0; b < 64; b++) NMS_STEP(s2, k2, b)
#pragma unroll 8
        for (int b = 0; b < 64; b++) NMS_STEP(s3, k3, b)
#pragma unroll 4
        for (int b = 0; b < 44; b++) NMS_STEP(s4, k4, b)
#undef NMS_STEP
        if (l == 0) {
            keepw[0] = k0; keepw[1] = k1; keepw[2] = k2; keepw[3] = k3; keepw[4] = k4;
        }
    }
    __syncthreads();

    // output 300 x 6
    for (int e = tid; e < 300 * 6; e += 1024) {
        int row = e / 6, col = e % 6;
        bool kept = (keepw[row >> 6] >> (row & 63)) & 1ull;
        float v = 0.0f;
        if (kept) {
            if (col < 4) {
                v = t_box[row][col] * (1.0f / 2048.0f);
                v = fminf(fmaxf(v, 0.0f), 1.0f);
            } else if (col == 4) {
                v = t_score[row];
            } else {
                v = (float)t_label[row];
            }
        }
        out[e] = v;
    }
}

// ---------------------------------------------------------------------------
extern "C" void kernel_launch(void* const* d_in, const int* in_sizes, int n_in,
                              void* d_out, int out_size, void* d_ws, size_t ws_size,
                              hipStream_t stream)
{
    const float* conf1 = (const float*)d_in[0];
    const float* cls1  = (const float*)d_in[1];
    const float* reg1  = (const float*)d_in[2];
    const float* anch1 = (const float*)d_in[3];
    const float* conf2 = (const float*)d_in[4];
    const float* cls2  = (const float*)d_in[5];
    const float* reg2  = (const float*)d_in[6];
    const float* anch2 = (const float*)d_in[7];
    const float* conf3 = (const float*)d_in[8];
    const float* cls3  = (const float*)d_in[9];
    const float* reg3  = (const float*)d_in[10];
    const float* anch3 = (const float*)d_in[11];

    int N1 = in_sizes[0];   // 196608
    int N2 = in_sizes[4];   // 49152
    int N3 = in_sizes[8];   // 12288

    unsigned int* wsu    = (unsigned int*)d_ws;
    unsigned int* hist   = wsu;                               // [3][NCOPY][NBUCKET]
    unsigned int* thresh = wsu + NLVL * NCOPY * NBUCKET;      // [3]
    unsigned int* ccount = thresh + NLVL;                     // [3]
    float*        amax   = (float*)(wsu + NLVL * NCOPY * NBUCKET + 16);   // [N1+N2+N3], 16B aligned
    float*        cscore = amax + (N1 + N2 + N3);                         // [3][CAP]
    unsigned int* cidx   = (unsigned int*)(cscore + NLVL * CAP);          // [3][CAP]

    hipMemsetAsync(hist, 0, (size_t)(NLVL * NCOPY * NBUCKET) * sizeof(unsigned int), stream);

    passA_kernel<<<PA_G1 + PA_G2 + PA_G3, 256, 0, stream>>>(
        conf1, cls1, conf2, cls2, conf3, cls3, N1, N2, N3, hist, amax);

    scan_kernel<<<NLVL, 256, 0, stream>>>(hist, thresh, ccount);

    compact_kernel<<<CK_G1 + CK_G2 + CK_G3, 256, 0, stream>>>(
        conf1, cls1, conf2, cls2, conf3, cls3, N1, N2, N3,
        thresh, amax, ccount, cscore, cidx);

    finalize_kernel<<<1, 1024, 0, stream>>>(reg1, anch1, reg2, anch2, reg3, anch3,
                                            cscore, cidx, ccount, (float*)d_out);
}

// Round 3
// 121.984 us; speedup vs baseline: 1.5810x; 1.2228x over previous
//
#include <hip/hip_runtime.h>
#include <math.h>

#define NBUCKET 4096
#define NCOPY   8
#define CAP     16384
#define QCAP    4096
#define STAGE   4096
#define FCAP    1024
#define TOPK    100
#define NLVL    3
#define NCLS    80

// block counts per level for passA / compact
#define PA_G1 1024
#define PA_G2 256
#define PA_G3 64
#define CK_G1 192
#define CK_G2 48
#define CK_G3 12

// ---------------------------------------------------------------------------
// Pass A: per-anchor max prob (= sigmoid/sum, exact max of the 80 probs),
// stored to amax[]; histogram of its float-bit key (>>18, monotonic for
// positive floats).  ONE shared-mem atomic per anchor.
// ---------------------------------------------------------------------------
__global__ void passA_kernel(const float* __restrict__ conf1, const float* __restrict__ cls1,
                             const float* __restrict__ conf2, const float* __restrict__ cls2,
                             const float* __restrict__ conf3, const float* __restrict__ cls3,
                             int n1, int n2, int n3,
                             unsigned int* __restrict__ ghist,
                             float* __restrict__ amax)
{
    const float* conf; const float* cls; int nA, nb, b;
    unsigned int* gh; float* am;
    if (blockIdx.x < PA_G1) {
        b = blockIdx.x; conf = conf1; cls = cls1; nA = n1; nb = PA_G1;
        gh = ghist; am = amax;
    } else if (blockIdx.x < PA_G1 + PA_G2) {
        b = blockIdx.x - PA_G1; conf = conf2; cls = cls2; nA = n2; nb = PA_G2;
        gh = ghist + NCOPY * NBUCKET; am = amax + n1;
    } else {
        b = blockIdx.x - PA_G1 - PA_G2; conf = conf3; cls = cls3; nA = n3; nb = PA_G3;
        gh = ghist + 2 * NCOPY * NBUCKET; am = amax + n1 + n2;
    }

    __shared__ unsigned int sh[NBUCKET];
    for (int i = threadIdx.x; i < NBUCKET; i += 256) sh[i] = 0;
    __syncthreads();

    int sub = threadIdx.x & 15;
    int g16 = threadIdx.x >> 4;
    int nChunk = nA >> 4;
    for (int ch = b; ch < nChunk; ch += nb) {
        int a = (ch << 4) + g16;
        float cv  = conf[a];
        float sig = 1.0f / (1.0f + expf(-cv));
        const float* row = cls + (size_t)a * NCLS + sub;
        float c0 = row[0], c1 = row[16], c2 = row[32], c3 = row[48], c4 = row[64];
        float m = fmaxf(fmaxf(fmaxf(c0, c1), fmaxf(c2, c3)), c4);
#pragma unroll
        for (int o = 8; o >= 1; o >>= 1) m = fmaxf(m, __shfl_xor(m, o, 16));
        float s = ((expf(c0 - m) + expf(c1 - m)) + (expf(c2 - m) + expf(c3 - m))) + expf(c4 - m);
#pragma unroll
        for (int o = 8; o >= 1; o >>= 1) s += __shfl_xor(s, o, 16);
        float inv = sig / s;                 // == max over the 80 probs, exactly
        if (sub == 0) {
            am[a] = inv;
            unsigned bk = __float_as_uint(inv) >> 18;
            if (bk > NBUCKET - 1) bk = NBUCKET - 1;
            atomicAdd(&sh[bk], 1u);
        }
    }
    __syncthreads();
    unsigned int* g = gh + (b & (NCOPY - 1)) * NBUCKET;
    for (int i = threadIdx.x; i < NBUCKET; i += 256) {
        unsigned v = sh[i];
        if (v) atomicAdd(&g[i], v);
    }
}

// ---------------------------------------------------------------------------
// Scan: per level, smallest bucket B with (# anchor-maxes in buckets >= B)
// >= TOPK.  Threshold key = B<<18.  Also zeroes ccount for compact.
// ---------------------------------------------------------------------------
__global__ void scan_kernel(const unsigned int* __restrict__ ghist,
                            unsigned int* __restrict__ thresh,
                            unsigned int* __restrict__ ccount)
{
    int lvl = blockIdx.x;
    const unsigned int* h0 = ghist + lvl * NCOPY * NBUCKET;
    __shared__ unsigned int h[NBUCKET];
    __shared__ unsigned int ps[256];
    int t = threadIdx.x;
    if (t == 0) ccount[lvl] = 0;
    for (int bb = t; bb < NBUCKET; bb += 256) {
        unsigned s = 0;
        for (int c = 0; c < NCOPY; c++) s += h0[c * NBUCKET + bb];
        h[bb] = s;
    }
    __syncthreads();
    unsigned cs = 0;
#pragma unroll
    for (int i = 0; i < 16; i++) cs += h[NBUCKET - 1 - (t * 16 + i)];
    ps[t] = cs;
    __syncthreads();
    for (int o = 1; o < 256; o <<= 1) {
        unsigned v = (t >= o) ? ps[t - o] : 0u;
        __syncthreads();
        ps[t] += v;
        __syncthreads();
    }
    unsigned incl = ps[t], excl = incl - cs;
    if (excl < TOPK && incl >= TOPK) {
        unsigned cum = excl, B = 0;
        for (int i = 0; i < 16; i++) {
            int bb = NBUCKET - 1 - (t * 16 + i);
            cum += h[bb];
            if (cum >= TOPK) { B = (unsigned)bb; break; }
        }
        thresh[lvl] = B << 18;
    }
}

// ---------------------------------------------------------------------------
// Compact: scan the amax array (float4), queue qualifying anchors in LDS,
// then recompute their 80 probs (bit-identical 16-lane routine) and emit
// (score, flat_idx) for every class with key >= T (max class unconditional).
// ---------------------------------------------------------------------------
__global__ void compact_kernel(const float* __restrict__ conf1, const float* __restrict__ cls1,
                               const float* __restrict__ conf2, const float* __restrict__ cls2,
                               const float* __restrict__ conf3, const float* __restrict__ cls3,
                               int n1, int n2, int n3,
                               const unsigned int* __restrict__ thresh,
                               const float* __restrict__ amax,
                               unsigned int* __restrict__ ccount,
                               float* __restrict__ cscore,
                               unsigned int* __restrict__ cidx)
{
    const float* conf; const float* cls; int bl, lvl; const float* am;
    if (blockIdx.x < CK_G1)              { lvl = 0; bl = blockIdx.x;               conf = conf1; cls = cls1; am = amax; }
    else if (blockIdx.x < CK_G1 + CK_G2) { lvl = 1; bl = blockIdx.x - CK_G1;       conf = conf2; cls = cls2; am = amax + n1; }
    else                                 { lvl = 2; bl = blockIdx.x - CK_G1 - CK_G2; conf = conf3; cls = cls3; am = amax + n1 + n2; }

    __shared__ int qn;
    __shared__ int queue[QCAP];
    if (threadIdx.x == 0) qn = 0;
    __syncthreads();

    unsigned T = thresh[lvl];
    int idx4 = bl * 256 + threadIdx.x;
    const float4* am4 = (const float4*)am;
    float4 v = am4[idx4];
    float vv[4] = {v.x, v.y, v.z, v.w};
#pragma unroll
    for (int j = 0; j < 4; j++) {
        if (__float_as_uint(vv[j]) >= T) {
            int p = atomicAdd(&qn, 1);
            if (p < QCAP) queue[p] = idx4 * 4 + j;
        }
    }
    __syncthreads();
    int qcnt = min(qn, QCAP);
    int grp = threadIdx.x >> 4;
    int sub = threadIdx.x & 15;
    float*        csl = cscore + lvl * CAP;
    unsigned int* cil = cidx   + lvl * CAP;
    for (int q = grp; q < qcnt; q += 16) {
        int a = queue[q];
        float cv  = conf[a];
        float sig = 1.0f / (1.0f + expf(-cv));
        const float* row = cls + (size_t)a * NCLS + sub;
        float c0 = row[0], c1 = row[16], c2 = row[32], c3 = row[48], c4 = row[64];
        float m = fmaxf(fmaxf(fmaxf(c0, c1), fmaxf(c2, c3)), c4);
#pragma unroll
        for (int o = 8; o >= 1; o >>= 1) m = fmaxf(m, __shfl_xor(m, o, 16));
        float e0 = expf(c0 - m), e1 = expf(c1 - m), e2 = expf(c2 - m),
              e3 = expf(c3 - m), e4 = expf(c4 - m);
        float s = ((e0 + e1) + (e2 + e3)) + e4;
#pragma unroll
        for (int o = 8; o >= 1; o >>= 1) s += __shfl_xor(s, o, 16);
        float inv = sig / s;
        float e[5] = {e0, e1, e2, e3, e4};
#pragma unroll
        for (int k = 0; k < 5; k++) {
            float p = e[k] * inv;
            if (e[k] == 1.0f || __float_as_uint(p) >= T) {
                unsigned pos = atomicAdd(&ccount[lvl], 1u);
                if (pos < CAP) {
                    csl[pos] = p;
                    cil[pos] = (unsigned)(a * NCLS + sub + 16 * k);
                }
            }
        }
    }
}

// ---------------------------------------------------------------------------
// Finalize: per level, stage the ~2k coarse candidates, refine the threshold
// with a 4096-bin sub-histogram of bits (key>>6 relative to the coarse
// bucket), filter to ~100 survivors, exact rank-selection on those; then
// box decode, stable global sort, register-resident wave NMS, output.
// ---------------------------------------------------------------------------
__global__ __launch_bounds__(1024) void finalize_kernel(
    const float* __restrict__ reg1, const float* __restrict__ anch1,
    const float* __restrict__ reg2, const float* __restrict__ anch2,
    const float* __restrict__ reg3, const float* __restrict__ anch3,
    const float* __restrict__ cscore, const unsigned int* __restrict__ cidx,
    const unsigned int* __restrict__ ccount,
    const unsigned int* __restrict__ thresh,
    float* __restrict__ out)
{
    int tid = threadIdx.x;
    __shared__ float        q_sc[STAGE];
    __shared__ unsigned int q_ix[STAGE];
    __shared__ unsigned int subh[4096];
    __shared__ unsigned int ps[1024];
    __shared__ unsigned int kthr_s;
    __shared__ int          fcnt;
    __shared__ float        f_sc[FCAP];
    __shared__ unsigned int f_ix[FCAP];
    __shared__ float s_score[300];
    __shared__ int   s_idx[300];
    __shared__ float s_box[300][4];
    __shared__ int   s_label[300];
    __shared__ int   s_valid[300];
    __shared__ float t_score[300];
    __shared__ float t_box[300][4];
    __shared__ int   t_label[300];
    __shared__ int   t_valid[300];
    __shared__ unsigned long long sup[300][5];
    __shared__ unsigned long long keepw[5];

    // per-level refined top-100
    for (int lvl = 0; lvl < NLVL; lvl++) {
        int cnt = min((int)ccount[lvl], CAP);
        const float*        sc = cscore + lvl * CAP;
        const unsigned int* ix = cidx   + lvl * CAP;
        int n = min(cnt, STAGE);
        unsigned B12 = (thresh[lvl] >> 18) << 12;
        __syncthreads();
        for (int i = tid; i < 4096; i += 1024) subh[i] = 0;
        if (tid == 0) fcnt = 0;
        for (int c = tid; c < n; c += 1024) { q_sc[c] = sc[c]; q_ix[c] = ix[c]; }
        __syncthreads();

        // sub-histogram of relative refined keys
        for (int c = tid; c < cnt; c += 1024) {
            float v = (c < n) ? q_sc[c] : sc[c];
            unsigned rel = (__float_as_uint(v) >> 6) - B12;
            if (rel > 4095u) rel = 4095u;
            atomicAdd(&subh[rel], 1u);
        }
        __syncthreads();

        // descending prefix scan: thread t covers {4095-4t, .., 4092-4t}
        unsigned cs = 0;
#pragma unroll
        for (int i = 0; i < 4; i++) cs += subh[4095 - 4 * tid - i];
        ps[tid] = cs;
        __syncthreads();
        for (int o = 1; o < 1024; o <<= 1) {
            unsigned v = (tid >= o) ? ps[tid - o] : 0u;
            __syncthreads();
            ps[tid] += v;
            __syncthreads();
        }
        {
            unsigned incl = ps[tid], excl = incl - cs;
            if (excl < TOPK && incl >= TOPK) {
                unsigned cum = excl;
                for (int i = 0; i < 4; i++) {
                    int sb = 4095 - 4 * tid - i;
                    cum += subh[sb];
                    if (cum >= TOPK) { kthr_s = (B12 + (unsigned)sb) << 6; break; }
                }
            }
        }
        __syncthreads();
        unsigned kthr = kthr_s;

        // filter to ~100 survivors
        for (int c = tid; c < cnt; c += 1024) {
            float v; unsigned vi;
            if (c < n) { v = q_sc[c]; vi = q_ix[c]; }
            else       { v = sc[c];   vi = ix[c];   }
            if (__float_as_uint(v) >= kthr) {
                int p = atomicAdd(&fcnt, 1);
                if (p < FCAP) { f_sc[p] = v; f_ix[p] = vi; }
            }
        }
        __syncthreads();
        int fn = min(fcnt, FCAP);

        // exact rank selection among the survivors
        for (int c = tid; c < fn; c += 1024) {
            float    my  = f_sc[c];
            unsigned myi = f_ix[c];
            int rank = 0;
            for (int k = 0; k < fn; k++) {
                float v = f_sc[k];
                rank += (v > my) || (v == my && f_ix[k] < myi);
            }
            if (rank < TOPK) {
                s_score[lvl * TOPK + rank] = my;
                s_idx[lvl * TOPK + rank]   = (int)myi;
            }
        }
        __syncthreads();
    }

    // box decode
    if (tid < 300) {
        int lvl = tid / TOPK;
        const float* reg = lvl == 0 ? reg1 : (lvl == 1 ? reg2 : reg3);
        const float* anc = lvl == 0 ? anch1 : (lvl == 1 ? anch2 : anch3);
        float stride = lvl == 0 ? 8.0f : (lvl == 1 ? 16.0f : 32.0f);
        int idx = s_idx[tid];
        int a   = idx / NCLS;
        int lab = idx % NCLS;
        float r0 = reg[4 * a + 0], r1 = reg[4 * a + 1], r2 = reg[4 * a + 2], r3 = reg[4 * a + 3];
        float a0 = anc[4 * a + 0], a1 = anc[4 * a + 1], a2 = anc[4 * a + 2], a3 = anc[4 * a + 3];
        float cx = (1.0f / (1.0f + expf(-r0)) + a0) * stride;
        float cy = (1.0f / (1.0f + expf(-r1)) + a1) * stride;
        float w  = expf(r2) * a2;
        float h  = expf(r3) * a3;
        s_box[tid][0] = cx - 0.5f * w;
        s_box[tid][1] = cy - 0.5f * h;
        s_box[tid][2] = cx + 0.5f * w;
        s_box[tid][3] = cy + 0.5f * h;
        s_label[tid] = lab;
        s_valid[tid] = s_score[tid] > 0.001f;
    }
    __syncthreads();

    // stable global sort: (score desc, position asc)
    if (tid < 300) {
        float my = s_score[tid];
        int rank = 0;
        for (int k = 0; k < 300; k++) {
            float v = s_score[k];
            rank += (v > my) || (v == my && k < tid);
        }
        t_score[rank]  = my;
        t_label[rank]  = s_label[tid];
        t_valid[rank]  = s_valid[tid];
        t_box[rank][0] = s_box[tid][0];
        t_box[rank][1] = s_box[tid][1];
        t_box[rank][2] = s_box[tid][2];
        t_box[rank][3] = s_box[tid][3];
    }
    __syncthreads();

    // suppression matrix (parallel build)
    for (int p = tid; p < 300 * 5; p += 1024) {
        int i = p / 5, w = p % 5;
        unsigned long long bits = 0;
        float x1 = t_box[i][0], y1 = t_box[i][1], x2 = t_box[i][2], y2 = t_box[i][3];
        float areai = (x2 - x1) * (y2 - y1);
        int labi = t_label[i];
        int j0 = w * 64;
        int j1 = min(j0 + 64, 300);
        for (int j = max(j0, i + 1); j < j1; j++) {
            if (t_label[j] != labi) continue;
            float xx1 = fmaxf(x1, t_box[j][0]);
            float yy1 = fmaxf(y1, t_box[j][1]);
            float xx2 = fminf(x2, t_box[j][2]);
            float yy2 = fminf(y2, t_box[j][3]);
            float ww = fmaxf(1e-10f, xx2 - xx1);
            float hh = fmaxf(1e-10f, yy2 - yy1);
            float inter = ww * hh;
            float areaj = (t_box[j][2] - t_box[j][0]) * (t_box[j][3] - t_box[j][1]);
            float iou = inter / (areai + areaj - inter);
            if (iou > 0.5f) bits |= 1ull << (j - j0);
        }
        sup[i][w] = bits;
    }
    if (tid < 5) {
        unsigned long long kw = 0;
        for (int bb = 0; bb < 64; bb++) {
            int j = tid * 64 + bb;
            if (j < 300 && t_valid[j]) kw |= 1ull << bb;
        }
        keepw[tid] = kw;
    }
    __syncthreads();

    // register-resident wave NMS: lane l of wave 0 owns rows l, l+64, ...
    if (tid < 64) {
        int l = tid;
        unsigned long long s0[5], s1[5], s2[5], s3[5], s4[5];
#pragma unroll
        for (int w = 0; w < 5; w++) {
            s0[w] = sup[l][w];
            s1[w] = sup[l + 64][w];
            s2[w] = sup[l + 128][w];
            s3[w] = sup[l + 192][w];
            s4[w] = (l + 256 < 300) ? sup[l + 256][w] : 0ull;
        }
        unsigned long long k0 = keepw[0], k1 = keepw[1], k2 = keepw[2],
                           k3 = keepw[3], k4 = keepw[4];
#define NMS_STEP(SR, KR, B)                                                   \
        {                                                                     \
            unsigned long long msk = 0ull - (unsigned long long)((KR >> (B)) & 1ull); \
            k0 &= ~(__shfl(SR[0], (B)) & msk);                                \
            k1 &= ~(__shfl(SR[1], (B)) & msk);                                \
            k2 &= ~(__shfl(SR[2], (B)) & msk);                                \
            k3 &= ~(__shfl(SR[3], (B)) & msk);                                \
            k4 &= ~(__shfl(SR[4], (B)) & msk);                                \
        }
#pragma unroll 8
        for (int b = 0; b < 64; b++) NMS_STEP(s0, k0, b)
#pragma unroll 8
        for (int b = 0; b < 64; b++) NMS_STEP(s1, k1, b)
#pragma unroll 8
        for (int b = 0; b < 64; b++) NMS_STEP(s2, k2, b)
#pragma unroll 8
        for (int b = 0; b < 64; b++) NMS_STEP(s3, k3, b)
#pragma unroll 4
        for (int b = 0; b < 44; b++) NMS_STEP(s4, k4, b)
#undef NMS_STEP
        if (l == 0) {
            keepw[0] = k0; keepw[1] = k1; keepw[2] = k2; keepw[3] = k3; keepw[4] = k4;
        }
    }
    __syncthreads();

    // output 300 x 6
    for (int e = tid; e < 300 * 6; e += 1024) {
        int row = e / 6, col = e % 6;
        bool kept = (keepw[row >> 6] >> (row & 63)) & 1ull;
        float v = 0.0f;
        if (kept) {
            if (col < 4) {
                v = t_box[row][col] * (1.0f / 2048.0f);
                v = fminf(fmaxf(v, 0.0f), 1.0f);
            } else if (col == 4) {
                v = t_score[row];
            } else {
                v = (float)t_label[row];
            }
        }
        out[e] = v;
    }
}

// ---------------------------------------------------------------------------
extern "C" void kernel_launch(void* const* d_in, const int* in_sizes, int n_in,
                              void* d_out, int out_size, void* d_ws, size_t ws_size,
                              hipStream_t stream)
{
    const float* conf1 = (const float*)d_in[0];
    const float* cls1  = (const float*)d_in[1];
    const float* reg1  = (const float*)d_in[2];
    const float* anch1 = (const float*)d_in[3];
    const float* conf2 = (const float*)d_in[4];
    const float* cls2  = (const float*)d_in[5];
    const float* reg2  = (const float*)d_in[6];
    const float* anch2 = (const float*)d_in[7];
    const float* conf3 = (const float*)d_in[8];
    const float* cls3  = (const float*)d_in[9];
    const float* reg3  = (const float*)d_in[10];
    const float* anch3 = (const float*)d_in[11];

    int N1 = in_sizes[0];   // 196608
    int N2 = in_sizes[4];   // 49152
    int N3 = in_sizes[8];   // 12288

    unsigned int* wsu    = (unsigned int*)d_ws;
    unsigned int* hist   = wsu;                               // [3][NCOPY][NBUCKET]
    unsigned int* thresh = wsu + NLVL * NCOPY * NBUCKET;      // [3]
    unsigned int* ccount = thresh + NLVL;                     // [3]
    float*        amax   = (float*)(wsu + NLVL * NCOPY * NBUCKET + 16);   // [N1+N2+N3], 16B aligned
    float*        cscore = amax + (N1 + N2 + N3);                         // [3][CAP]
    unsigned int* cidx   = (unsigned int*)(cscore + NLVL * CAP);          // [3][CAP]

    hipMemsetAsync(hist, 0, (size_t)(NLVL * NCOPY * NBUCKET) * sizeof(unsigned int), stream);

    passA_kernel<<<PA_G1 + PA_G2 + PA_G3, 256, 0, stream>>>(
        conf1, cls1, conf2, cls2, conf3, cls3, N1, N2, N3, hist, amax);

    scan_kernel<<<NLVL, 256, 0, stream>>>(hist, thresh, ccount);

    compact_kernel<<<CK_G1 + CK_G2 + CK_G3, 256, 0, stream>>>(
        conf1, cls1, conf2, cls2, conf3, cls3, N1, N2, N3,
        thresh, amax, ccount, cscore, cidx);

    finalize_kernel<<<1, 1024, 0, stream>>>(reg1, anch1, reg2, anch2, reg3, anch3,
                                            cscore, cidx, ccount, thresh, (float*)d_out);
}

// Round 4
// 118.013 us; speedup vs baseline: 1.6342x; 1.0337x over previous
//
#include <hip/hip_runtime.h>
#include <math.h>

#define NBUCKET 4096
#define NCOPY   8
#define CAP     16384
#define QCAP    4096
#define STAGE   4096
#define FCAP    1024
#define TOPK    100
#define NLVL    3
#define NCLS    80

// block counts per level for passA / compact
#define PA_G1 1024
#define PA_G2 256
#define PA_G3 64
#define CK_G1 192
#define CK_G2 48
#define CK_G3 12

// ---------------------------------------------------------------------------
// Pass A: per-anchor max prob (= sigmoid/sum, exact max of the 80 probs),
// stored to amax[]; histogram of its float-bit key (>>18, monotonic for
// positive floats).  ONE shared-mem atomic per anchor.
// ---------------------------------------------------------------------------
__global__ void passA_kernel(const float* __restrict__ conf1, const float* __restrict__ cls1,
                             const float* __restrict__ conf2, const float* __restrict__ cls2,
                             const float* __restrict__ conf3, const float* __restrict__ cls3,
                             int n1, int n2, int n3,
                             unsigned int* __restrict__ ghist,
                             float* __restrict__ amax)
{
    const float* conf; const float* cls; int nA, nb, b;
    unsigned int* gh; float* am;
    if (blockIdx.x < PA_G1) {
        b = blockIdx.x; conf = conf1; cls = cls1; nA = n1; nb = PA_G1;
        gh = ghist; am = amax;
    } else if (blockIdx.x < PA_G1 + PA_G2) {
        b = blockIdx.x - PA_G1; conf = conf2; cls = cls2; nA = n2; nb = PA_G2;
        gh = ghist + NCOPY * NBUCKET; am = amax + n1;
    } else {
        b = blockIdx.x - PA_G1 - PA_G2; conf = conf3; cls = cls3; nA = n3; nb = PA_G3;
        gh = ghist + 2 * NCOPY * NBUCKET; am = amax + n1 + n2;
    }

    __shared__ unsigned int sh[NBUCKET];
    for (int i = threadIdx.x; i < NBUCKET; i += 256) sh[i] = 0;
    __syncthreads();

    int sub = threadIdx.x & 15;
    int g16 = threadIdx.x >> 4;
    int nChunk = nA >> 4;
    for (int ch = b; ch < nChunk; ch += nb) {
        int a = (ch << 4) + g16;
        float cv  = conf[a];
        float sig = 1.0f / (1.0f + expf(-cv));
        const float* row = cls + (size_t)a * NCLS + sub;
        float c0 = row[0], c1 = row[16], c2 = row[32], c3 = row[48], c4 = row[64];
        float m = fmaxf(fmaxf(fmaxf(c0, c1), fmaxf(c2, c3)), c4);
#pragma unroll
        for (int o = 8; o >= 1; o >>= 1) m = fmaxf(m, __shfl_xor(m, o, 16));
        float s = ((expf(c0 - m) + expf(c1 - m)) + (expf(c2 - m) + expf(c3 - m))) + expf(c4 - m);
#pragma unroll
        for (int o = 8; o >= 1; o >>= 1) s += __shfl_xor(s, o, 16);
        float inv = sig / s;                 // == max over the 80 probs, exactly
        if (sub == 0) {
            am[a] = inv;
            unsigned bk = __float_as_uint(inv) >> 18;
            if (bk > NBUCKET - 1) bk = NBUCKET - 1;
            atomicAdd(&sh[bk], 1u);
        }
    }
    __syncthreads();
    unsigned int* g = gh + (b & (NCOPY - 1)) * NBUCKET;
    for (int i = threadIdx.x; i < NBUCKET; i += 256) {
        unsigned v = sh[i];
        if (v) atomicAdd(&g[i], v);
    }
}

// ---------------------------------------------------------------------------
// Scan: per level, smallest bucket B with (# anchor-maxes in buckets >= B)
// >= TOPK.  Threshold key = B<<18.  Also zeroes ccount for compact.
// ---------------------------------------------------------------------------
__global__ void scan_kernel(const unsigned int* __restrict__ ghist,
                            unsigned int* __restrict__ thresh,
                            unsigned int* __restrict__ ccount)
{
    int lvl = blockIdx.x;
    const unsigned int* h0 = ghist + lvl * NCOPY * NBUCKET;
    __shared__ unsigned int h[NBUCKET];
    __shared__ unsigned int ps[256];
    int t = threadIdx.x;
    if (t == 0) ccount[lvl] = 0;
    for (int bb = t; bb < NBUCKET; bb += 256) {
        unsigned s = 0;
        for (int c = 0; c < NCOPY; c++) s += h0[c * NBUCKET + bb];
        h[bb] = s;
    }
    __syncthreads();
    unsigned cs = 0;
#pragma unroll
    for (int i = 0; i < 16; i++) cs += h[NBUCKET - 1 - (t * 16 + i)];
    ps[t] = cs;
    __syncthreads();
    for (int o = 1; o < 256; o <<= 1) {
        unsigned v = (t >= o) ? ps[t - o] : 0u;
        __syncthreads();
        ps[t] += v;
        __syncthreads();
    }
    unsigned incl = ps[t], excl = incl - cs;
    if (excl < TOPK && incl >= TOPK) {
        unsigned cum = excl, B = 0;
        for (int i = 0; i < 16; i++) {
            int bb = NBUCKET - 1 - (t * 16 + i);
            cum += h[bb];
            if (cum >= TOPK) { B = (unsigned)bb; break; }
        }
        thresh[lvl] = B << 18;
    }
}

// ---------------------------------------------------------------------------
// Compact: scan the amax array (float4), queue qualifying anchors in LDS,
// then recompute their 80 probs (bit-identical 16-lane routine) and emit
// (score, flat_idx) for every class with key >= T (max class unconditional).
// ---------------------------------------------------------------------------
__global__ void compact_kernel(const float* __restrict__ conf1, const float* __restrict__ cls1,
                               const float* __restrict__ conf2, const float* __restrict__ cls2,
                               const float* __restrict__ conf3, const float* __restrict__ cls3,
                               int n1, int n2, int n3,
                               const unsigned int* __restrict__ thresh,
                               const float* __restrict__ amax,
                               unsigned int* __restrict__ ccount,
                               float* __restrict__ cscore,
                               unsigned int* __restrict__ cidx)
{
    const float* conf; const float* cls; int bl, lvl; const float* am;
    if (blockIdx.x < CK_G1)              { lvl = 0; bl = blockIdx.x;               conf = conf1; cls = cls1; am = amax; }
    else if (blockIdx.x < CK_G1 + CK_G2) { lvl = 1; bl = blockIdx.x - CK_G1;       conf = conf2; cls = cls2; am = amax + n1; }
    else                                 { lvl = 2; bl = blockIdx.x - CK_G1 - CK_G2; conf = conf3; cls = cls3; am = amax + n1 + n2; }

    __shared__ int qn;
    __shared__ int queue[QCAP];
    if (threadIdx.x == 0) qn = 0;
    __syncthreads();

    unsigned T = thresh[lvl];
    int idx4 = bl * 256 + threadIdx.x;
    const float4* am4 = (const float4*)am;
    float4 v = am4[idx4];
    float vv[4] = {v.x, v.y, v.z, v.w};
#pragma unroll
    for (int j = 0; j < 4; j++) {
        if (__float_as_uint(vv[j]) >= T) {
            int p = atomicAdd(&qn, 1);
            if (p < QCAP) queue[p] = idx4 * 4 + j;
        }
    }
    __syncthreads();
    int qcnt = min(qn, QCAP);
    int grp = threadIdx.x >> 4;
    int sub = threadIdx.x & 15;
    float*        csl = cscore + lvl * CAP;
    unsigned int* cil = cidx   + lvl * CAP;
    for (int q = grp; q < qcnt; q += 16) {
        int a = queue[q];
        float cv  = conf[a];
        float sig = 1.0f / (1.0f + expf(-cv));
        const float* row = cls + (size_t)a * NCLS + sub;
        float c0 = row[0], c1 = row[16], c2 = row[32], c3 = row[48], c4 = row[64];
        float m = fmaxf(fmaxf(fmaxf(c0, c1), fmaxf(c2, c3)), c4);
#pragma unroll
        for (int o = 8; o >= 1; o >>= 1) m = fmaxf(m, __shfl_xor(m, o, 16));
        float e0 = expf(c0 - m), e1 = expf(c1 - m), e2 = expf(c2 - m),
              e3 = expf(c3 - m), e4 = expf(c4 - m);
        float s = ((e0 + e1) + (e2 + e3)) + e4;
#pragma unroll
        for (int o = 8; o >= 1; o >>= 1) s += __shfl_xor(s, o, 16);
        float inv = sig / s;
        float e[5] = {e0, e1, e2, e3, e4};
#pragma unroll
        for (int k = 0; k < 5; k++) {
            float p = e[k] * inv;
            if (e[k] == 1.0f || __float_as_uint(p) >= T) {
                unsigned pos = atomicAdd(&ccount[lvl], 1u);
                if (pos < CAP) {
                    csl[pos] = p;
                    cil[pos] = (unsigned)(a * NCLS + sub + 16 * k);
                }
            }
        }
    }
}

// ---------------------------------------------------------------------------
// Select: ONE BLOCK PER LEVEL (grid=3, parallel CUs).  Stage candidates,
// refine threshold via 4096-bin sub-histogram of (key>>6) relative to the
// coarse bucket, filter to ~100 survivors, exact rank-selection (score desc,
// idx asc), write per-level top-100 to workspace.
// ---------------------------------------------------------------------------
__global__ __launch_bounds__(1024) void select_kernel(
    const float* __restrict__ cscore, const unsigned int* __restrict__ cidx,
    const unsigned int* __restrict__ ccount,
    const unsigned int* __restrict__ thresh,
    float* __restrict__ sel_sc, int* __restrict__ sel_ix)
{
    int lvl = blockIdx.x;
    int tid = threadIdx.x;
    __shared__ float        q_sc[STAGE];
    __shared__ unsigned int q_ix[STAGE];
    __shared__ unsigned int subh[4096];
    __shared__ unsigned int ps[1024];
    __shared__ unsigned int kthr_s;
    __shared__ int          fcnt;
    __shared__ float        f_sc[FCAP];
    __shared__ unsigned int f_ix[FCAP];

    int cnt = min((int)ccount[lvl], CAP);
    const float*        sc = cscore + lvl * CAP;
    const unsigned int* ix = cidx   + lvl * CAP;
    int n = min(cnt, STAGE);
    unsigned B12 = (thresh[lvl] >> 18) << 12;

    for (int i = tid; i < 4096; i += 1024) subh[i] = 0;
    if (tid == 0) fcnt = 0;
    for (int c = tid; c < n; c += 1024) { q_sc[c] = sc[c]; q_ix[c] = ix[c]; }
    // safety init of output (ranks are guaranteed filled when fn >= 100)
    if (tid < TOPK) { sel_sc[lvl * TOPK + tid] = -1e30f; sel_ix[lvl * TOPK + tid] = 0; }
    __syncthreads();

    // sub-histogram of relative refined keys
    for (int c = tid; c < cnt; c += 1024) {
        float v = (c < n) ? q_sc[c] : sc[c];
        unsigned rel = (__float_as_uint(v) >> 6) - B12;
        if (rel > 4095u) rel = 4095u;
        atomicAdd(&subh[rel], 1u);
    }
    __syncthreads();

    // descending prefix scan: thread t covers {4095-4t, .., 4092-4t}
    unsigned cs = 0;
#pragma unroll
    for (int i = 0; i < 4; i++) cs += subh[4095 - 4 * tid - i];
    ps[tid] = cs;
    __syncthreads();
    for (int o = 1; o < 1024; o <<= 1) {
        unsigned v = (tid >= o) ? ps[tid - o] : 0u;
        __syncthreads();
        ps[tid] += v;
        __syncthreads();
    }
    {
        unsigned incl = ps[tid], excl = incl - cs;
        if (excl < TOPK && incl >= TOPK) {
            unsigned cum = excl;
            for (int i = 0; i < 4; i++) {
                int sb = 4095 - 4 * tid - i;
                cum += subh[sb];
                if (cum >= TOPK) { kthr_s = (B12 + (unsigned)sb) << 6; break; }
            }
        }
    }
    __syncthreads();
    unsigned kthr = kthr_s;

    // filter to ~100 survivors
    for (int c = tid; c < cnt; c += 1024) {
        float v; unsigned vi;
        if (c < n) { v = q_sc[c]; vi = q_ix[c]; }
        else       { v = sc[c];   vi = ix[c];   }
        if (__float_as_uint(v) >= kthr) {
            int p = atomicAdd(&fcnt, 1);
            if (p < FCAP) { f_sc[p] = v; f_ix[p] = vi; }
        }
    }
    __syncthreads();
    int fn = min(fcnt, FCAP);

    // exact rank selection among the survivors
    for (int c = tid; c < fn; c += 1024) {
        float    my  = f_sc[c];
        unsigned myi = f_ix[c];
        int rank = 0;
        for (int k = 0; k < fn; k++) {
            float v = f_sc[k];
            rank += (v > my) || (v == my && f_ix[k] < myi);
        }
        if (rank < TOPK) {
            sel_sc[lvl * TOPK + rank] = my;
            sel_ix[lvl * TOPK + rank] = (int)myi;
        }
    }
}

// ---------------------------------------------------------------------------
// Final: 1 block, 512 threads.  Decode 300 boxes, stable global sort
// (score desc, pos asc), suppression matrix, register-wave NMS, output.
// ---------------------------------------------------------------------------
__global__ __launch_bounds__(512) void final_kernel(
    const float* __restrict__ reg1, const float* __restrict__ anch1,
    const float* __restrict__ reg2, const float* __restrict__ anch2,
    const float* __restrict__ reg3, const float* __restrict__ anch3,
    const float* __restrict__ sel_sc, const int* __restrict__ sel_ix,
    float* __restrict__ out)
{
    int tid = threadIdx.x;
    __shared__ float s_score[300];
    __shared__ float s_box[300][4];
    __shared__ int   s_label[300];
    __shared__ int   s_valid[300];
    __shared__ float t_score[300];
    __shared__ float t_box[300][4];
    __shared__ int   t_label[300];
    __shared__ int   t_valid[300];
    __shared__ unsigned long long sup[300][5];
    __shared__ unsigned long long keepw[5];

    // load + decode
    if (tid < 300) {
        int lvl = tid / TOPK;
        const float* reg = lvl == 0 ? reg1 : (lvl == 1 ? reg2 : reg3);
        const float* anc = lvl == 0 ? anch1 : (lvl == 1 ? anch2 : anch3);
        float stride = lvl == 0 ? 8.0f : (lvl == 1 ? 16.0f : 32.0f);
        float sc = sel_sc[tid];
        int  idx = sel_ix[tid];
        int a   = idx / NCLS;
        int lab = idx % NCLS;
        float r0 = reg[4 * a + 0], r1 = reg[4 * a + 1], r2 = reg[4 * a + 2], r3 = reg[4 * a + 3];
        float a0 = anc[4 * a + 0], a1 = anc[4 * a + 1], a2 = anc[4 * a + 2], a3 = anc[4 * a + 3];
        float cx = (1.0f / (1.0f + expf(-r0)) + a0) * stride;
        float cy = (1.0f / (1.0f + expf(-r1)) + a1) * stride;
        float w  = expf(r2) * a2;
        float h  = expf(r3) * a3;
        s_score[tid]  = sc;
        s_box[tid][0] = cx - 0.5f * w;
        s_box[tid][1] = cy - 0.5f * h;
        s_box[tid][2] = cx + 0.5f * w;
        s_box[tid][3] = cy + 0.5f * h;
        s_label[tid] = lab;
        s_valid[tid] = sc > 0.001f;
    }
    __syncthreads();

    // stable global sort: (score desc, position asc)
    if (tid < 300) {
        float my = s_score[tid];
        int rank = 0;
        for (int k = 0; k < 300; k++) {
            float v = s_score[k];
            rank += (v > my) || (v == my && k < tid);
        }
        t_score[rank]  = my;
        t_label[rank]  = s_label[tid];
        t_valid[rank]  = s_valid[tid];
        t_box[rank][0] = s_box[tid][0];
        t_box[rank][1] = s_box[tid][1];
        t_box[rank][2] = s_box[tid][2];
        t_box[rank][3] = s_box[tid][3];
    }
    __syncthreads();

    // suppression matrix (parallel build)
    for (int p = tid; p < 300 * 5; p += 512) {
        int i = p / 5, w = p % 5;
        unsigned long long bits = 0;
        float x1 = t_box[i][0], y1 = t_box[i][1], x2 = t_box[i][2], y2 = t_box[i][3];
        float areai = (x2 - x1) * (y2 - y1);
        int labi = t_label[i];
        int j0 = w * 64;
        int j1 = min(j0 + 64, 300);
        for (int j = max(j0, i + 1); j < j1; j++) {
            if (t_label[j] != labi) continue;
            float xx1 = fmaxf(x1, t_box[j][0]);
            float yy1 = fmaxf(y1, t_box[j][1]);
            float xx2 = fminf(x2, t_box[j][2]);
            float yy2 = fminf(y2, t_box[j][3]);
            float ww = fmaxf(1e-10f, xx2 - xx1);
            float hh = fmaxf(1e-10f, yy2 - yy1);
            float inter = ww * hh;
            float areaj = (t_box[j][2] - t_box[j][0]) * (t_box[j][3] - t_box[j][1]);
            float iou = inter / (areai + areaj - inter);
            if (iou > 0.5f) bits |= 1ull << (j - j0);
        }
        sup[i][w] = bits;
    }
    if (tid < 5) {
        unsigned long long kw = 0;
        for (int bb = 0; bb < 64; bb++) {
            int j = tid * 64 + bb;
            if (j < 300 && t_valid[j]) kw |= 1ull << bb;
        }
        keepw[tid] = kw;
    }
    __syncthreads();

    // register-resident wave NMS: lane l of wave 0 owns rows l, l+64, ...
    if (tid < 64) {
        int l = tid;
        unsigned long long s0[5], s1[5], s2[5], s3[5], s4[5];
#pragma unroll
        for (int w = 0; w < 5; w++) {
            s0[w] = sup[l][w];
            s1[w] = sup[l + 64][w];
            s2[w] = sup[l + 128][w];
            s3[w] = sup[l + 192][w];
            s4[w] = (l + 256 < 300) ? sup[l + 256][w] : 0ull;
        }
        unsigned long long k0 = keepw[0], k1 = keepw[1], k2 = keepw[2],
                           k3 = keepw[3], k4 = keepw[4];
#define NMS_STEP(SR, KR, B)                                                   \
        {                                                                     \
            unsigned long long msk = 0ull - (unsigned long long)((KR >> (B)) & 1ull); \
            k0 &= ~(__shfl(SR[0], (B)) & msk);                                \
            k1 &= ~(__shfl(SR[1], (B)) & msk);                                \
            k2 &= ~(__shfl(SR[2], (B)) & msk);                                \
            k3 &= ~(__shfl(SR[3], (B)) & msk);                                \
            k4 &= ~(__shfl(SR[4], (B)) & msk);                                \
        }
#pragma unroll 8
        for (int b = 0; b < 64; b++) NMS_STEP(s0, k0, b)
#pragma unroll 8
        for (int b = 0; b < 64; b++) NMS_STEP(s1, k1, b)
#pragma unroll 8
        for (int b = 0; b < 64; b++) NMS_STEP(s2, k2, b)
#pragma unroll 8
        for (int b = 0; b < 64; b++) NMS_STEP(s3, k3, b)
#pragma unroll 4
        for (int b = 0; b < 44; b++) NMS_STEP(s4, k4, b)
#undef NMS_STEP
        if (l == 0) {
            keepw[0] = k0; keepw[1] = k1; keepw[2] = k2; keepw[3] = k3; keepw[4] = k4;
        }
    }
    __syncthreads();

    // output 300 x 6
    for (int e = tid; e < 300 * 6; e += 512) {
        int row = e / 6, col = e % 6;
        bool kept = (keepw[row >> 6] >> (row & 63)) & 1ull;
        float v = 0.0f;
        if (kept) {
            if (col < 4) {
                v = t_box[row][col] * (1.0f / 2048.0f);
                v = fminf(fmaxf(v, 0.0f), 1.0f);
            } else if (col == 4) {
                v = t_score[row];
            } else {
                v = (float)t_label[row];
            }
        }
        out[e] = v;
    }
}

// ---------------------------------------------------------------------------
extern "C" void kernel_launch(void* const* d_in, const int* in_sizes, int n_in,
                              void* d_out, int out_size, void* d_ws, size_t ws_size,
                              hipStream_t stream)
{
    const float* conf1 = (const float*)d_in[0];
    const float* cls1  = (const float*)d_in[1];
    const float* reg1  = (const float*)d_in[2];
    const float* anch1 = (const float*)d_in[3];
    const float* conf2 = (const float*)d_in[4];
    const float* cls2  = (const float*)d_in[5];
    const float* reg2  = (const float*)d_in[6];
    const float* anch2 = (const float*)d_in[7];
    const float* conf3 = (const float*)d_in[8];
    const float* cls3  = (const float*)d_in[9];
    const float* reg3  = (const float*)d_in[10];
    const float* anch3 = (const float*)d_in[11];

    int N1 = in_sizes[0];   // 196608
    int N2 = in_sizes[4];   // 49152
    int N3 = in_sizes[8];   // 12288

    unsigned int* wsu    = (unsigned int*)d_ws;
    unsigned int* hist   = wsu;                               // [3][NCOPY][NBUCKET]
    unsigned int* thresh = wsu + NLVL * NCOPY * NBUCKET;      // [3]
    unsigned int* ccount = thresh + NLVL;                     // [3]
    float*        amax   = (float*)(wsu + NLVL * NCOPY * NBUCKET + 16);   // [N1+N2+N3], 16B aligned
    float*        cscore = amax + (N1 + N2 + N3);                         // [3][CAP]
    unsigned int* cidx   = (unsigned int*)(cscore + NLVL * CAP);          // [3][CAP]
    float*        sel_sc = (float*)(cidx + NLVL * CAP);                   // [300]
    int*          sel_ix = (int*)(sel_sc + NLVL * TOPK);                  // [300]

    hipMemsetAsync(hist, 0, (size_t)(NLVL * NCOPY * NBUCKET) * sizeof(unsigned int), stream);

    passA_kernel<<<PA_G1 + PA_G2 + PA_G3, 256, 0, stream>>>(
        conf1, cls1, conf2, cls2, conf3, cls3, N1, N2, N3, hist, amax);

    scan_kernel<<<NLVL, 256, 0, stream>>>(hist, thresh, ccount);

    compact_kernel<<<CK_G1 + CK_G2 + CK_G3, 256, 0, stream>>>(
        conf1, cls1, conf2, cls2, conf3, cls3, N1, N2, N3,
        thresh, amax, ccount, cscore, cidx);

    select_kernel<<<NLVL, 1024, 0, stream>>>(cscore, cidx, ccount, thresh, sel_sc, sel_ix);

    final_kernel<<<1, 512, 0, stream>>>(reg1, anch1, reg2, anch2, reg3, anch3,
                                        sel_sc, sel_ix, (float*)d_out);
}